// Round 4
// baseline (656.355 us; speedup 1.0000x reference)
//
#include <hip/hip_runtime.h>
#include <math.h>

#define PIX 4096
#define O_CH 512
#define CV_PITCH 68   // f32 words per phi row in LDS
#define NY_PITCH 32   // u32 (bf16x2) per ny row in LDS

typedef __attribute__((ext_vector_type(8))) short s16x8;
typedef __attribute__((ext_vector_type(4))) float f32x4;

__device__ __forceinline__ ushort f2bf(float f) {
  unsigned u = __float_as_uint(f);
  return (ushort)((u + 0x7fffu + ((u >> 16) & 1u)) >> 16);
}
__device__ __forceinline__ float bf2f(ushort h) {
  return __uint_as_float(((unsigned)h) << 16);
}
__device__ __forceinline__ unsigned pk_bf2(float lo, float hi) {
  unsigned ulo = (__float_as_uint(lo) + 0x8000u) >> 16;
  unsigned uhi = (__float_as_uint(hi) + 0x8000u) & 0xffff0000u;
  return ulo | uhi;
}

// ---------------- merged MFMA GEMM (split-bf16, ~fp32 accurate) ----------------
// bz<8: z[b] = relu(g_w*g[b]) + x_w*x[b];  bz>=8: phi0[b] = c_w*contour[b]
__global__ __launch_bounds__(256, 2) void mfma_gemm_all(
    const float* __restrict__ g, const float* __restrict__ x,
    const float* __restrict__ contour,
    const float* __restrict__ g_w, const float* __restrict__ x_w,
    const float* __restrict__ c_w,
    float* __restrict__ z, float* __restrict__ phi0)
{
  __shared__ ushort WHs[8192], WLs[8192], AHs[8192], ALs[8192];  // 64 KB
  const int t = threadIdx.x;
  const int lane = t & 63, wave = t >> 6;
  const int wm = wave >> 1, wn = wave & 1;
  const int rowA = lane & 15, kg = lane >> 4;
  const int pb = blockIdx.x * 128, ob = blockIdx.y * 128;
  const int bz = blockIdx.z;
  const bool isZ = bz < 8;
  const int b = isZ ? bz : bz - 8;

  const float* W1 = isZ ? g_w : c_w;
  const int K1 = 256;
  const float* A1 = (isZ ? g : contour) + (size_t)b * K1 * PIX;
  const float* W2 = isZ ? x_w : nullptr;
  const int K2 = 512;
  const float* A2 = isZ ? x + (size_t)b * K2 * PIX : nullptr;
  float* out = (isZ ? z : phi0) + (size_t)b * O_CH * PIX;

  f32x4 acc[4][4];
#pragma unroll
  for (int mi = 0; mi < 4; ++mi)
#pragma unroll
    for (int ni = 0; ni < 4; ++ni) acc[mi][ni] = (f32x4){0.f, 0.f, 0.f, 0.f};

  for (int pass = 0; pass < 2; ++pass) {
    if (pass == 1 && W2 == nullptr) break;
    const float* W = pass ? W2 : W1;
    const int K = pass ? K2 : K1;
    const float* A = pass ? A2 : A1;

    for (int kb = 0; kb < K; kb += 64) {
      {
        const int o_r = t >> 1, hf = t & 1;
        const float* wrow = W + (size_t)(ob + o_r) * K + kb + hf * 32;
#pragma unroll
        for (int i = 0; i < 8; ++i) {
          float4 v = *(const float4*)(wrow + i * 4);
          ushort h0 = f2bf(v.x), h1 = f2bf(v.y), h2 = f2bf(v.z), h3 = f2bf(v.w);
          ushort l0 = f2bf(v.x - bf2f(h0)), l1 = f2bf(v.y - bf2f(h1));
          ushort l2 = f2bf(v.z - bf2f(h2)), l3 = f2bf(v.w - bf2f(h3));
          int grp = hf * 4 + (i >> 1);
          int idx = o_r * 64 + ((grp ^ (o_r & 7)) << 3) + (i & 1) * 4;
          *(ushort4*)&WHs[idx] = make_ushort4(h0, h1, h2, h3);
          *(ushort4*)&WLs[idx] = make_ushort4(l0, l1, l2, l3);
        }
      }
#pragma unroll
      for (int ph = 0; ph < 2; ++ph) {
        const int rp = ph * 64 + lane;
        const float* ac = A + (size_t)kb * PIX + pb + rp;
#pragma unroll
        for (int ch = 0; ch < 2; ++ch) {
          const int kloc0 = ch * 32 + wave * 8;
          float v[8];
#pragma unroll
          for (int j = 0; j < 8; ++j) v[j] = ac[(size_t)(kloc0 + j) * PIX];
          ushort hs[8], lsv[8];
#pragma unroll
          for (int j = 0; j < 8; ++j) {
            ushort hb = f2bf(v[j]);
            hs[j] = hb;
            lsv[j] = f2bf(v[j] - bf2f(hb));
          }
          int grp = ch * 4 + wave;
          int idx = rp * 64 + ((grp ^ (rp & 7)) << 3);
          *(ushort4*)&AHs[idx]     = make_ushort4(hs[0], hs[1], hs[2], hs[3]);
          *(ushort4*)&AHs[idx + 4] = make_ushort4(hs[4], hs[5], hs[6], hs[7]);
          *(ushort4*)&ALs[idx]     = make_ushort4(lsv[0], lsv[1], lsv[2], lsv[3]);
          *(ushort4*)&ALs[idx + 4] = make_ushort4(lsv[4], lsv[5], lsv[6], lsv[7]);
        }
      }
      __syncthreads();
#pragma unroll
      for (int ks = 0; ks < 2; ++ks) {
        s16x8 wh[4], wlv[4], ah[4], alv[4];
#pragma unroll
        for (int mi = 0; mi < 4; ++mi) {
          int row = wm * 64 + mi * 16 + rowA;
          int idx = row * 64 + (((ks * 4 + kg) ^ (row & 7)) << 3);
          wh[mi]  = *(const s16x8*)&WHs[idx];
          wlv[mi] = *(const s16x8*)&WLs[idx];
        }
#pragma unroll
        for (int ni = 0; ni < 4; ++ni) {
          int row = wn * 64 + ni * 16 + rowA;
          int idx = row * 64 + (((ks * 4 + kg) ^ (row & 7)) << 3);
          ah[ni]  = *(const s16x8*)&AHs[idx];
          alv[ni] = *(const s16x8*)&ALs[idx];
        }
#pragma unroll
        for (int mi = 0; mi < 4; ++mi)
#pragma unroll
          for (int ni = 0; ni < 4; ++ni) {
            acc[mi][ni] = __builtin_amdgcn_mfma_f32_16x16x32_bf16(wh[mi],  ah[ni],  acc[mi][ni], 0, 0, 0);
            acc[mi][ni] = __builtin_amdgcn_mfma_f32_16x16x32_bf16(wh[mi],  alv[ni], acc[mi][ni], 0, 0, 0);
            acc[mi][ni] = __builtin_amdgcn_mfma_f32_16x16x32_bf16(wlv[mi], ah[ni],  acc[mi][ni], 0, 0, 0);
          }
      }
      __syncthreads();
    }
    if (pass == 0 && isZ) {
#pragma unroll
      for (int mi = 0; mi < 4; ++mi)
#pragma unroll
        for (int ni = 0; ni < 4; ++ni)
#pragma unroll
          for (int r = 0; r < 4; ++r) acc[mi][ni][r] = fmaxf(acc[mi][ni][r], 0.f);
    }
  }
  const int orow = (lane >> 4) * 4, pcol = lane & 15;
#pragma unroll
  for (int mi = 0; mi < 4; ++mi)
#pragma unroll
    for (int ni = 0; ni < 4; ++ni)
#pragma unroll
      for (int r = 0; r < 4; ++r)
        out[(size_t)(ob + wm * 64 + mi * 16 + orow + r) * PIX +
            pb + wn * 64 + ni * 16 + pcol] = acc[mi][ni][r];
}

// ---------------- Chan-Vese ----------------
__device__ __forceinline__ float fast_atan(float x) {
  float a = __builtin_fabsf(x);
  float inv = __builtin_amdgcn_rcpf(a);
  bool big = a > 1.f;
  float tt = big ? inv : a;
  float t2 = tt * tt;
  float p = fmaf(t2, 0.0208351f, -0.0851330f);
  p = fmaf(t2, p, 0.1801410f);
  p = fmaf(t2, p, -0.3302995f);
  p = fmaf(t2, p, 0.9998660f);
  p = p * tt;
  float r = big ? (1.57079632679f - p) : p;
  return __builtin_copysignf(r, x);
}

__global__ __launch_bounds__(256, 6) void chanvese(
    const float* __restrict__ zb, float* __restrict__ ob,
    const float* __restrict__ dtp, const float* __restrict__ lamp)
{
  __shared__ float phi_l[64 * CV_PITCH];     // 17408 B
  __shared__ unsigned ny_l[64 * NY_PITCH];   // 8192 B (bf16x2)
  __shared__ float red[12];
  const int t = threadIdx.x;
  const int lane = t & 63, wv = t >> 6;
  const int row = t >> 2, s = t & 3;
  const int col0 = s * 16;
  const size_t gbase = (size_t)blockIdx.x * PIX + row * 64 + col0;
  const float dtv = dtp[0], lam = lamp[0];
  const float INV_PI = 0.31830988618379067f;
  const float dtpi = dtv * INV_PI;
  const float fy = (row == 0 || row == 63) ? 1.f : 0.5f;
  const float fx0 = (s == 0) ? 1.f : 0.5f;
  const float fx15 = (s == 3) ? 1.f : 0.5f;
  const int my = row * CV_PITCH + col0;
  const int ub = ((row == 0) ? 0 : row - 1) * CV_PITCH + col0;
  const int db = ((row == 63) ? 63 : row + 1) * CV_PITCH + col0;
  const int myn = row * NY_PITCH + s * 8;
  const int ubn = ((row == 0) ? 0 : row - 1) * NY_PITCH + s * 8;
  const int dbn = ((row == 63) ? 63 : row + 1) * NY_PITCH + s * 8;

  float I[16], phi[16], nx[16];
#pragma unroll
  for (int q = 0; q < 4; ++q) {
    float4 iv = *(const float4*)(zb + gbase + q * 4);
    float4 pv = *(const float4*)(ob + gbase + q * 4);
    I[q * 4 + 0] = iv.x; I[q * 4 + 1] = iv.y; I[q * 4 + 2] = iv.z; I[q * 4 + 3] = iv.w;
    phi[q * 4 + 0] = pv.x; phi[q * 4 + 1] = pv.y; phi[q * 4 + 2] = pv.z; phi[q * 4 + 3] = pv.w;
    *(float4*)&phi_l[my + q * 4] = pv;
  }
  float sI = 0.f, s_at = 0.f, s_iat = 0.f;
#pragma unroll
  for (int j = 0; j < 16; ++j) {
    sI += I[j];
    float at = fast_atan(phi[j]);
    s_at += at;
    s_iat = fmaf(I[j], at, s_iat);
  }
#pragma unroll
  for (int off = 32; off; off >>= 1) {
    sI += __shfl_xor(sI, off);
    s_at += __shfl_xor(s_at, off);
    s_iat += __shfl_xor(s_iat, off);
  }
  if (lane == 0) { red[wv] = s_at; red[4 + wv] = s_iat; red[8 + wv] = sI; }
  __syncthreads();
  float S_at = red[0] + red[1] + red[2] + red[3];
  float S_iat = red[4] + red[5] + red[6] + red[7];
  const float sumI = red[8] + red[9] + red[10] + red[11];

  for (int it = 0; it < 10; ++it) {
    float a1 = fmaf(INV_PI, S_at, 2048.f);
    float sIH = fmaf(INV_PI, S_iat, 0.5f * sumI);
    float c1 = sIH * __builtin_amdgcn_rcpf(a1 + 1e-8f);
    float c2 = (sumI - sIH) * __builtin_amdgcn_rcpf(4096.f - a1 + 1e-8f);
    float lam12 = lam * (c1 - c2);
    float s12 = c1 + c2;

    // ---- pass 1: normals; nx in regs, ny -> LDS bf16 pairs ----
    float u[16], d[16];
#pragma unroll
    for (int q = 0; q < 4; ++q) {
      float4 uv = *(const float4*)&phi_l[ub + q * 4];
      float4 dv = *(const float4*)&phi_l[db + q * 4];
      u[q * 4 + 0] = uv.x; u[q * 4 + 1] = uv.y; u[q * 4 + 2] = uv.z; u[q * 4 + 3] = uv.w;
      d[q * 4 + 0] = dv.x; d[q * 4 + 1] = dv.y; d[q * 4 + 2] = dv.z; d[q * 4 + 3] = dv.w;
    }
    float ls = __shfl(phi[15], lane - 1);
    float rs = __shfl(phi[0], lane + 1);
    unsigned nyp[8];
#pragma unroll
    for (int j = 0; j < 16; j += 2) {
      float l0 = (j == 0) ? ((s == 0) ? phi[0] : ls) : phi[j - 1];
      float fx0j = (j == 0) ? fx0 : 0.5f;
      float px0 = (phi[j + 1] - l0) * fx0j;
      float r1 = (j == 14) ? ((s == 3) ? phi[15] : rs) : phi[j + 2];
      float fx1j = (j == 14) ? fx15 : 0.5f;
      float px1 = (r1 - phi[j]) * fx1j;
      float py0 = (d[j] - u[j]) * fy;
      float py1 = (d[j + 1] - u[j + 1]) * fy;
      float rn0 = __builtin_amdgcn_rsqf(fmaf(px0, px0, fmaf(py0, py0, 1e-8f)));
      float rn1 = __builtin_amdgcn_rsqf(fmaf(px1, px1, fmaf(py1, py1, 1e-8f)));
      nx[j] = px0 * rn0;
      nx[j + 1] = px1 * rn1;
      nyp[j >> 1] = pk_bf2(py0 * rn0, py1 * rn1);
    }
    *(uint4*)&ny_l[myn]     = make_uint4(nyp[0], nyp[1], nyp[2], nyp[3]);
    *(uint4*)&ny_l[myn + 4] = make_uint4(nyp[4], nyp[5], nyp[6], nyp[7]);
    __syncthreads();

    // ---- pass 2: curvature + update + incremental sums ----
    float nyu[16], nyd[16];
    {
      uint4 a0 = *(const uint4*)&ny_l[ubn];
      uint4 a1v = *(const uint4*)&ny_l[ubn + 4];
      uint4 b0 = *(const uint4*)&ny_l[dbn];
      uint4 b1 = *(const uint4*)&ny_l[dbn + 4];
      unsigned ua[8] = {a0.x, a0.y, a0.z, a0.w, a1v.x, a1v.y, a1v.z, a1v.w};
      unsigned ud[8] = {b0.x, b0.y, b0.z, b0.w, b1.x, b1.y, b1.z, b1.w};
#pragma unroll
      for (int p = 0; p < 8; ++p) {
        nyu[2 * p]     = __uint_as_float(ua[p] << 16);
        nyu[2 * p + 1] = __uint_as_float(ua[p] & 0xffff0000u);
        nyd[2 * p]     = __uint_as_float(ud[p] << 16);
        nyd[2 * p + 1] = __uint_as_float(ud[p] & 0xffff0000u);
      }
    }
    float nls = __shfl(nx[15], lane - 1);
    float nrs = __shfl(nx[0], lane + 1);
    float inc_at = 0.f, inc_iat = 0.f;
#pragma unroll
    for (int j = 0; j < 16; ++j) {
      float nl = (j == 0) ? ((s == 0) ? nx[0] : nls) : nx[j - 1];
      float nr = (j == 15) ? ((s == 3) ? nx[15] : nrs) : nx[j + 1];
      float fxj = (j == 0) ? fx0 : ((j == 15) ? fx15 : 0.5f);
      float curv = fmaf(nyd[j] - nyu[j], fy, (nr - nl) * fxj);
      float c = phi[j];
      float rcd = __builtin_amdgcn_rcpf(fmaf(c, c, 1.f));
      float force = fmaf(lam12, fmaf(2.f, I[j], -s12), curv);
      float dphi = dtpi * rcd * force;
      phi[j] = c + dphi;
      float da = dphi * rcd;   // atan'(phi)*dphi
      inc_at += da;
      inc_iat = fmaf(I[j], da, inc_iat);
    }
    if (it < 9) {
#pragma unroll
      for (int q = 0; q < 4; ++q)
        *(float4*)&phi_l[my + q * 4] =
            make_float4(phi[q * 4], phi[q * 4 + 1], phi[q * 4 + 2], phi[q * 4 + 3]);
#pragma unroll
      for (int off = 32; off; off >>= 1) {
        inc_at += __shfl_xor(inc_at, off);
        inc_iat += __shfl_xor(inc_iat, off);
      }
      if (lane == 0) { red[2 * wv] = inc_at; red[2 * wv + 1] = inc_iat; }
      __syncthreads();
      S_at += red[0] + red[2] + red[4] + red[6];
      S_iat += red[1] + red[3] + red[5] + red[7];
    }
  }

#pragma unroll
  for (int q = 0; q < 4; ++q) {
    float o0 = 1.f / (1.f + exp2f(phi[q * 4 + 0] * -1.44269504089f));
    float o1 = 1.f / (1.f + exp2f(phi[q * 4 + 1] * -1.44269504089f));
    float o2 = 1.f / (1.f + exp2f(phi[q * 4 + 2] * -1.44269504089f));
    float o3 = 1.f / (1.f + exp2f(phi[q * 4 + 3] * -1.44269504089f));
    *(float4*)(ob + gbase + q * 4) = make_float4(o0, o1, o2, o3);
  }
}

extern "C" void kernel_launch(void* const* d_in, const int* in_sizes, int n_in,
                              void* d_out, int out_size, void* d_ws, size_t ws_size,
                              hipStream_t stream)
{
  const float* contour = (const float*)d_in[0];
  const float* g       = (const float*)d_in[1];
  const float* x       = (const float*)d_in[2];
  const float* dt      = (const float*)d_in[3];
  const float* lam     = (const float*)d_in[4];
  const float* g_w     = (const float*)d_in[5];
  const float* x_w     = (const float*)d_in[6];
  const float* c_w     = (const float*)d_in[7];
  float* out = (float*)d_out;
  float* z   = (float*)d_ws;  // [8,512,64,64] f32 = 67 MB

  mfma_gemm_all<<<dim3(32, 4, 16), dim3(256), 0, stream>>>(
      g, x, contour, g_w, x_w, c_w, z, out);
  chanvese<<<dim3(4096), dim3(256), 0, stream>>>(z, out, dt, lam);
}

// Round 5
// 299.870 us; speedup vs baseline: 2.1888x; 2.1888x over previous
//
#include <hip/hip_runtime.h>
#include <math.h>

#define PIX 4096
#define O_CH 512
#define CV_PITCH 68   // f32 words per phi row in LDS
#define NY_PITCH 32   // u32 (bf16x2) per ny row in LDS

typedef __attribute__((ext_vector_type(8))) short s16x8;
typedef __attribute__((ext_vector_type(4))) float f32x4;

__device__ __forceinline__ ushort f2bf(float f) {
  unsigned u = __float_as_uint(f);
  return (ushort)((u + 0x7fffu + ((u >> 16) & 1u)) >> 16);
}
__device__ __forceinline__ float bf2f(ushort h) {
  return __uint_as_float(((unsigned)h) << 16);
}
__device__ __forceinline__ unsigned pk_bf2(float lo, float hi) {
  unsigned ulo = (__float_as_uint(lo) + 0x8000u) >> 16;
  unsigned uhi = (__float_as_uint(hi) + 0x8000u) & 0xffff0000u;
  return ulo | uhi;
}

// ---------------- merged MFMA GEMM (split-bf16, ~fp32 accurate) ----------------
// bz<8: z[b] = relu(g_w*g[b]) + x_w*x[b];  bz>=8: phi0[b] = c_w*contour[b]
__global__ __launch_bounds__(256, 2) void mfma_gemm_all(
    const float* __restrict__ g, const float* __restrict__ x,
    const float* __restrict__ contour,
    const float* __restrict__ g_w, const float* __restrict__ x_w,
    const float* __restrict__ c_w,
    float* __restrict__ z, float* __restrict__ phi0)
{
  __shared__ ushort WHs[8192], WLs[8192], AHs[8192], ALs[8192];  // 64 KB
  const int t = threadIdx.x;
  const int lane = t & 63, wave = t >> 6;
  const int wm = wave >> 1, wn = wave & 1;
  const int rowA = lane & 15, kg = lane >> 4;
  const int pb = blockIdx.x * 128, ob = blockIdx.y * 128;
  const int bz = blockIdx.z;
  const bool isZ = bz < 8;
  const int b = isZ ? bz : bz - 8;

  const float* W1 = isZ ? g_w : c_w;
  const int K1 = 256;
  const float* A1 = (isZ ? g : contour) + (size_t)b * K1 * PIX;
  const float* W2 = isZ ? x_w : nullptr;
  const int K2 = 512;
  const float* A2 = isZ ? x + (size_t)b * K2 * PIX : nullptr;
  float* out = (isZ ? z : phi0) + (size_t)b * O_CH * PIX;

  f32x4 acc[4][4];
#pragma unroll
  for (int mi = 0; mi < 4; ++mi)
#pragma unroll
    for (int ni = 0; ni < 4; ++ni) acc[mi][ni] = (f32x4){0.f, 0.f, 0.f, 0.f};

  for (int pass = 0; pass < 2; ++pass) {
    if (pass == 1 && W2 == nullptr) break;
    const float* W = pass ? W2 : W1;
    const int K = pass ? K2 : K1;
    const float* A = pass ? A2 : A1;

    for (int kb = 0; kb < K; kb += 64) {
      {
        const int o_r = t >> 1, hf = t & 1;
        const float* wrow = W + (size_t)(ob + o_r) * K + kb + hf * 32;
#pragma unroll
        for (int i = 0; i < 8; ++i) {
          float4 v = *(const float4*)(wrow + i * 4);
          ushort h0 = f2bf(v.x), h1 = f2bf(v.y), h2 = f2bf(v.z), h3 = f2bf(v.w);
          ushort l0 = f2bf(v.x - bf2f(h0)), l1 = f2bf(v.y - bf2f(h1));
          ushort l2 = f2bf(v.z - bf2f(h2)), l3 = f2bf(v.w - bf2f(h3));
          int grp = hf * 4 + (i >> 1);
          int idx = o_r * 64 + ((grp ^ (o_r & 7)) << 3) + (i & 1) * 4;
          *(ushort4*)&WHs[idx] = make_ushort4(h0, h1, h2, h3);
          *(ushort4*)&WLs[idx] = make_ushort4(l0, l1, l2, l3);
        }
      }
#pragma unroll
      for (int ph = 0; ph < 2; ++ph) {
        const int rp = ph * 64 + lane;
        const float* ac = A + (size_t)kb * PIX + pb + rp;
#pragma unroll
        for (int ch = 0; ch < 2; ++ch) {
          const int kloc0 = ch * 32 + wave * 8;
          float v[8];
#pragma unroll
          for (int j = 0; j < 8; ++j) v[j] = ac[(size_t)(kloc0 + j) * PIX];
          ushort hs[8], lsv[8];
#pragma unroll
          for (int j = 0; j < 8; ++j) {
            ushort hb = f2bf(v[j]);
            hs[j] = hb;
            lsv[j] = f2bf(v[j] - bf2f(hb));
          }
          int grp = ch * 4 + wave;
          int idx = rp * 64 + ((grp ^ (rp & 7)) << 3);
          *(ushort4*)&AHs[idx]     = make_ushort4(hs[0], hs[1], hs[2], hs[3]);
          *(ushort4*)&AHs[idx + 4] = make_ushort4(hs[4], hs[5], hs[6], hs[7]);
          *(ushort4*)&ALs[idx]     = make_ushort4(lsv[0], lsv[1], lsv[2], lsv[3]);
          *(ushort4*)&ALs[idx + 4] = make_ushort4(lsv[4], lsv[5], lsv[6], lsv[7]);
        }
      }
      __syncthreads();
#pragma unroll
      for (int ks = 0; ks < 2; ++ks) {
        s16x8 wh[4], wlv[4], ah[4], alv[4];
#pragma unroll
        for (int mi = 0; mi < 4; ++mi) {
          int row = wm * 64 + mi * 16 + rowA;
          int idx = row * 64 + (((ks * 4 + kg) ^ (row & 7)) << 3);
          wh[mi]  = *(const s16x8*)&WHs[idx];
          wlv[mi] = *(const s16x8*)&WLs[idx];
        }
#pragma unroll
        for (int ni = 0; ni < 4; ++ni) {
          int row = wn * 64 + ni * 16 + rowA;
          int idx = row * 64 + (((ks * 4 + kg) ^ (row & 7)) << 3);
          ah[ni]  = *(const s16x8*)&AHs[idx];
          alv[ni] = *(const s16x8*)&ALs[idx];
        }
#pragma unroll
        for (int mi = 0; mi < 4; ++mi)
#pragma unroll
          for (int ni = 0; ni < 4; ++ni) {
            acc[mi][ni] = __builtin_amdgcn_mfma_f32_16x16x32_bf16(wh[mi],  ah[ni],  acc[mi][ni], 0, 0, 0);
            acc[mi][ni] = __builtin_amdgcn_mfma_f32_16x16x32_bf16(wh[mi],  alv[ni], acc[mi][ni], 0, 0, 0);
            acc[mi][ni] = __builtin_amdgcn_mfma_f32_16x16x32_bf16(wlv[mi], ah[ni],  acc[mi][ni], 0, 0, 0);
          }
      }
      __syncthreads();
    }
    if (pass == 0 && isZ) {
#pragma unroll
      for (int mi = 0; mi < 4; ++mi)
#pragma unroll
        for (int ni = 0; ni < 4; ++ni)
#pragma unroll
          for (int r = 0; r < 4; ++r) acc[mi][ni][r] = fmaxf(acc[mi][ni][r], 0.f);
    }
  }
  const int orow = (lane >> 4) * 4, pcol = lane & 15;
#pragma unroll
  for (int mi = 0; mi < 4; ++mi)
#pragma unroll
    for (int ni = 0; ni < 4; ++ni)
#pragma unroll
      for (int r = 0; r < 4; ++r)
        out[(size_t)(ob + wm * 64 + mi * 16 + orow + r) * PIX +
            pb + wn * 64 + ni * 16 + pcol] = acc[mi][ni][r];
}

// ---------------- Chan-Vese ----------------
__device__ __forceinline__ float fast_atan(float x) {
  float a = __builtin_fabsf(x);
  float inv = __builtin_amdgcn_rcpf(a);
  bool big = a > 1.f;
  float tt = big ? inv : a;
  float t2 = tt * tt;
  float p = fmaf(t2, 0.0208351f, -0.0851330f);
  p = fmaf(t2, p, 0.1801410f);
  p = fmaf(t2, p, -0.3302995f);
  p = fmaf(t2, p, 0.9998660f);
  p = p * tt;
  float r = big ? (1.57079632679f - p) : p;
  return __builtin_copysignf(r, x);
}

// launch_bounds (256,4): VGPR cap 128 — round-3 allocation was 64 VGPR, no
// spill. (256,6) forced VGPR=40 -> full scratch spill -> 2.1 GB HBM traffic.
// Occupancy comes from the LDS shrink instead: 25.9 KB -> 6 blocks/CU (75%).
__global__ __launch_bounds__(256, 4) void chanvese(
    const float* __restrict__ zb, float* __restrict__ ob,
    const float* __restrict__ dtp, const float* __restrict__ lamp)
{
  __shared__ float phi_l[64 * CV_PITCH];     // 17408 B
  __shared__ unsigned ny_l[64 * NY_PITCH];   // 8192 B (bf16x2)
  __shared__ float red[12];
  const int t = threadIdx.x;
  const int lane = t & 63, wv = t >> 6;
  const int row = t >> 2, s = t & 3;
  const int col0 = s * 16;
  const size_t gbase = (size_t)blockIdx.x * PIX + row * 64 + col0;
  const float dtv = dtp[0], lam = lamp[0];
  const float INV_PI = 0.31830988618379067f;
  const float dtpi = dtv * INV_PI;
  const float fy = (row == 0 || row == 63) ? 1.f : 0.5f;
  const float fx0 = (s == 0) ? 1.f : 0.5f;
  const float fx15 = (s == 3) ? 1.f : 0.5f;
  const int my = row * CV_PITCH + col0;
  const int ub = ((row == 0) ? 0 : row - 1) * CV_PITCH + col0;
  const int db = ((row == 63) ? 63 : row + 1) * CV_PITCH + col0;
  const int myn = row * NY_PITCH + s * 8;
  const int ubn = ((row == 0) ? 0 : row - 1) * NY_PITCH + s * 8;
  const int dbn = ((row == 63) ? 63 : row + 1) * NY_PITCH + s * 8;

  float I[16], phi[16], nx[16];
#pragma unroll
  for (int q = 0; q < 4; ++q) {
    float4 iv = *(const float4*)(zb + gbase + q * 4);
    float4 pv = *(const float4*)(ob + gbase + q * 4);
    I[q * 4 + 0] = iv.x; I[q * 4 + 1] = iv.y; I[q * 4 + 2] = iv.z; I[q * 4 + 3] = iv.w;
    phi[q * 4 + 0] = pv.x; phi[q * 4 + 1] = pv.y; phi[q * 4 + 2] = pv.z; phi[q * 4 + 3] = pv.w;
    *(float4*)&phi_l[my + q * 4] = pv;
  }
  float sI = 0.f, s_at = 0.f, s_iat = 0.f;
#pragma unroll
  for (int j = 0; j < 16; ++j) {
    sI += I[j];
    float at = fast_atan(phi[j]);
    s_at += at;
    s_iat = fmaf(I[j], at, s_iat);
  }
#pragma unroll
  for (int off = 32; off; off >>= 1) {
    sI += __shfl_xor(sI, off);
    s_at += __shfl_xor(s_at, off);
    s_iat += __shfl_xor(s_iat, off);
  }
  if (lane == 0) { red[wv] = s_at; red[4 + wv] = s_iat; red[8 + wv] = sI; }
  __syncthreads();
  float S_at = red[0] + red[1] + red[2] + red[3];
  float S_iat = red[4] + red[5] + red[6] + red[7];
  const float sumI = red[8] + red[9] + red[10] + red[11];

  for (int it = 0; it < 10; ++it) {
    float a1 = fmaf(INV_PI, S_at, 2048.f);
    float sIH = fmaf(INV_PI, S_iat, 0.5f * sumI);
    float c1 = sIH * __builtin_amdgcn_rcpf(a1 + 1e-8f);
    float c2 = (sumI - sIH) * __builtin_amdgcn_rcpf(4096.f - a1 + 1e-8f);
    float lam12 = lam * (c1 - c2);
    float s12 = c1 + c2;

    // ---- pass 1: normals; nx in regs, ny -> LDS bf16 pairs ----
    float u[16], d[16];
#pragma unroll
    for (int q = 0; q < 4; ++q) {
      float4 uv = *(const float4*)&phi_l[ub + q * 4];
      float4 dv = *(const float4*)&phi_l[db + q * 4];
      u[q * 4 + 0] = uv.x; u[q * 4 + 1] = uv.y; u[q * 4 + 2] = uv.z; u[q * 4 + 3] = uv.w;
      d[q * 4 + 0] = dv.x; d[q * 4 + 1] = dv.y; d[q * 4 + 2] = dv.z; d[q * 4 + 3] = dv.w;
    }
    float ls = __shfl(phi[15], lane - 1);
    float rs = __shfl(phi[0], lane + 1);
    unsigned nyp[8];
#pragma unroll
    for (int j = 0; j < 16; j += 2) {
      float l0 = (j == 0) ? ((s == 0) ? phi[0] : ls) : phi[j - 1];
      float fx0j = (j == 0) ? fx0 : 0.5f;
      float px0 = (phi[j + 1] - l0) * fx0j;
      float r1 = (j == 14) ? ((s == 3) ? phi[15] : rs) : phi[j + 2];
      float fx1j = (j == 14) ? fx15 : 0.5f;
      float px1 = (r1 - phi[j]) * fx1j;
      float py0 = (d[j] - u[j]) * fy;
      float py1 = (d[j + 1] - u[j + 1]) * fy;
      float rn0 = __builtin_amdgcn_rsqf(fmaf(px0, px0, fmaf(py0, py0, 1e-8f)));
      float rn1 = __builtin_amdgcn_rsqf(fmaf(px1, px1, fmaf(py1, py1, 1e-8f)));
      nx[j] = px0 * rn0;
      nx[j + 1] = px1 * rn1;
      nyp[j >> 1] = pk_bf2(py0 * rn0, py1 * rn1);
    }
    *(uint4*)&ny_l[myn]     = make_uint4(nyp[0], nyp[1], nyp[2], nyp[3]);
    *(uint4*)&ny_l[myn + 4] = make_uint4(nyp[4], nyp[5], nyp[6], nyp[7]);
    __syncthreads();

    // ---- pass 2: curvature + update + incremental sums ----
    float nyu[16], nyd[16];
    {
      uint4 a0 = *(const uint4*)&ny_l[ubn];
      uint4 a1v = *(const uint4*)&ny_l[ubn + 4];
      uint4 b0 = *(const uint4*)&ny_l[dbn];
      uint4 b1 = *(const uint4*)&ny_l[dbn + 4];
      unsigned ua[8] = {a0.x, a0.y, a0.z, a0.w, a1v.x, a1v.y, a1v.z, a1v.w};
      unsigned ud[8] = {b0.x, b0.y, b0.z, b0.w, b1.x, b1.y, b1.z, b1.w};
#pragma unroll
      for (int p = 0; p < 8; ++p) {
        nyu[2 * p]     = __uint_as_float(ua[p] << 16);
        nyu[2 * p + 1] = __uint_as_float(ua[p] & 0xffff0000u);
        nyd[2 * p]     = __uint_as_float(ud[p] << 16);
        nyd[2 * p + 1] = __uint_as_float(ud[p] & 0xffff0000u);
      }
    }
    float nls = __shfl(nx[15], lane - 1);
    float nrs = __shfl(nx[0], lane + 1);
    float inc_at = 0.f, inc_iat = 0.f;
#pragma unroll
    for (int j = 0; j < 16; ++j) {
      float nl = (j == 0) ? ((s == 0) ? nx[0] : nls) : nx[j - 1];
      float nr = (j == 15) ? ((s == 3) ? nx[15] : nrs) : nx[j + 1];
      float fxj = (j == 0) ? fx0 : ((j == 15) ? fx15 : 0.5f);
      float curv = fmaf(nyd[j] - nyu[j], fy, (nr - nl) * fxj);
      float c = phi[j];
      float rcd = __builtin_amdgcn_rcpf(fmaf(c, c, 1.f));
      float force = fmaf(lam12, fmaf(2.f, I[j], -s12), curv);
      float dphi = dtpi * rcd * force;
      phi[j] = c + dphi;
      float da = dphi * rcd;   // atan'(phi)*dphi
      inc_at += da;
      inc_iat = fmaf(I[j], da, inc_iat);
    }
    if (it < 9) {
#pragma unroll
      for (int q = 0; q < 4; ++q)
        *(float4*)&phi_l[my + q * 4] =
            make_float4(phi[q * 4], phi[q * 4 + 1], phi[q * 4 + 2], phi[q * 4 + 3]);
#pragma unroll
      for (int off = 32; off; off >>= 1) {
        inc_at += __shfl_xor(inc_at, off);
        inc_iat += __shfl_xor(inc_iat, off);
      }
      if (lane == 0) { red[2 * wv] = inc_at; red[2 * wv + 1] = inc_iat; }
      __syncthreads();
      S_at += red[0] + red[2] + red[4] + red[6];
      S_iat += red[1] + red[3] + red[5] + red[7];
    }
  }

#pragma unroll
  for (int q = 0; q < 4; ++q) {
    float o0 = 1.f / (1.f + exp2f(phi[q * 4 + 0] * -1.44269504089f));
    float o1 = 1.f / (1.f + exp2f(phi[q * 4 + 1] * -1.44269504089f));
    float o2 = 1.f / (1.f + exp2f(phi[q * 4 + 2] * -1.44269504089f));
    float o3 = 1.f / (1.f + exp2f(phi[q * 4 + 3] * -1.44269504089f));
    *(float4*)(ob + gbase + q * 4) = make_float4(o0, o1, o2, o3);
  }
}

extern "C" void kernel_launch(void* const* d_in, const int* in_sizes, int n_in,
                              void* d_out, int out_size, void* d_ws, size_t ws_size,
                              hipStream_t stream)
{
  const float* contour = (const float*)d_in[0];
  const float* g       = (const float*)d_in[1];
  const float* x       = (const float*)d_in[2];
  const float* dt      = (const float*)d_in[3];
  const float* lam     = (const float*)d_in[4];
  const float* g_w     = (const float*)d_in[5];
  const float* x_w     = (const float*)d_in[6];
  const float* c_w     = (const float*)d_in[7];
  float* out = (float*)d_out;
  float* z   = (float*)d_ws;  // [8,512,64,64] f32 = 67 MB

  mfma_gemm_all<<<dim3(32, 4, 16), dim3(256), 0, stream>>>(
      g, x, contour, g_w, x_w, c_w, z, out);
  chanvese<<<dim3(4096), dim3(256), 0, stream>>>(z, out, dt, lam);
}

// Round 7
// 283.973 us; speedup vs baseline: 2.3113x; 1.0560x over previous
//
#include <hip/hip_runtime.h>
#include <math.h>

#define PIX 4096
#define O_CH 512
#define CV_PITCH 80   // f32 words per phi row in LDS (s-stride 20: quad=(4r+5s)%8 -> conflict-free)
#define CV_SSTR 20
#define NY_PITCH 36   // u32 per ny row (s-stride 8: quad=(r+2s+h)%8 -> conflict-free)

typedef __attribute__((ext_vector_type(8))) short s16x8;
typedef __attribute__((ext_vector_type(4))) float f32x4;
typedef __attribute__((ext_vector_type(2))) float f32x2;

__device__ __forceinline__ ushort f2bf(float f) {
  unsigned u = __float_as_uint(f);
  return (ushort)((u + 0x7fffu + ((u >> 16) & 1u)) >> 16);
}
__device__ __forceinline__ float bf2f(ushort h) {
  return __uint_as_float(((unsigned)h) << 16);
}

// ---------------- merged MFMA GEMM (split-bf16, ~fp32 accurate) ----------------
// bz<8: z[b] = relu(g_w*g[b]) + x_w*x[b];  bz>=8: phi0[b] = c_w*contour[b]
__global__ __launch_bounds__(256, 2) void mfma_gemm_all(
    const float* __restrict__ g, const float* __restrict__ x,
    const float* __restrict__ contour,
    const float* __restrict__ g_w, const float* __restrict__ x_w,
    const float* __restrict__ c_w,
    float* __restrict__ z, float* __restrict__ phi0)
{
  __shared__ ushort WHs[8192], WLs[8192], AHs[8192], ALs[8192];  // 64 KB
  const int t = threadIdx.x;
  const int lane = t & 63, wave = t >> 6;
  const int wm = wave >> 1, wn = wave & 1;
  const int rowA = lane & 15, kg = lane >> 4;
  const int pb = blockIdx.x * 128, ob = blockIdx.y * 128;
  const int bz = blockIdx.z;
  const bool isZ = bz < 8;
  const int b = isZ ? bz : bz - 8;

  const float* W1 = isZ ? g_w : c_w;
  const int K1 = 256;
  const float* A1 = (isZ ? g : contour) + (size_t)b * K1 * PIX;
  const float* W2 = isZ ? x_w : nullptr;
  const int K2 = 512;
  const float* A2 = isZ ? x + (size_t)b * K2 * PIX : nullptr;
  float* out = (isZ ? z : phi0) + (size_t)b * O_CH * PIX;

  f32x4 acc[4][4];
#pragma unroll
  for (int mi = 0; mi < 4; ++mi)
#pragma unroll
    for (int ni = 0; ni < 4; ++ni) acc[mi][ni] = (f32x4){0.f, 0.f, 0.f, 0.f};

  for (int pass = 0; pass < 2; ++pass) {
    if (pass == 1 && W2 == nullptr) break;
    const float* W = pass ? W2 : W1;
    const int K = pass ? K2 : K1;
    const float* A = pass ? A2 : A1;

    for (int kb = 0; kb < K; kb += 64) {
      {
        const int o_r = t >> 1, hf = t & 1;
        const float* wrow = W + (size_t)(ob + o_r) * K + kb + hf * 32;
#pragma unroll
        for (int i = 0; i < 8; ++i) {
          float4 v = *(const float4*)(wrow + i * 4);
          ushort h0 = f2bf(v.x), h1 = f2bf(v.y), h2 = f2bf(v.z), h3 = f2bf(v.w);
          ushort l0 = f2bf(v.x - bf2f(h0)), l1 = f2bf(v.y - bf2f(h1));
          ushort l2 = f2bf(v.z - bf2f(h2)), l3 = f2bf(v.w - bf2f(h3));
          int grp = hf * 4 + (i >> 1);
          int idx = o_r * 64 + ((grp ^ (o_r & 7)) << 3) + (i & 1) * 4;
          *(ushort4*)&WHs[idx] = make_ushort4(h0, h1, h2, h3);
          *(ushort4*)&WLs[idx] = make_ushort4(l0, l1, l2, l3);
        }
      }
#pragma unroll
      for (int ph = 0; ph < 2; ++ph) {
        const int rp = ph * 64 + lane;
        const float* ac = A + (size_t)kb * PIX + pb + rp;
#pragma unroll
        for (int ch = 0; ch < 2; ++ch) {
          const int kloc0 = ch * 32 + wave * 8;
          float v[8];
#pragma unroll
          for (int j = 0; j < 8; ++j) v[j] = ac[(size_t)(kloc0 + j) * PIX];
          ushort hs[8], lsv[8];
#pragma unroll
          for (int j = 0; j < 8; ++j) {
            ushort hb = f2bf(v[j]);
            hs[j] = hb;
            lsv[j] = f2bf(v[j] - bf2f(hb));
          }
          int grp = ch * 4 + wave;
          int idx = rp * 64 + ((grp ^ (rp & 7)) << 3);
          *(ushort4*)&AHs[idx]     = make_ushort4(hs[0], hs[1], hs[2], hs[3]);
          *(ushort4*)&AHs[idx + 4] = make_ushort4(hs[4], hs[5], hs[6], hs[7]);
          *(ushort4*)&ALs[idx]     = make_ushort4(lsv[0], lsv[1], lsv[2], lsv[3]);
          *(ushort4*)&ALs[idx + 4] = make_ushort4(lsv[4], lsv[5], lsv[6], lsv[7]);
        }
      }
      __syncthreads();
#pragma unroll
      for (int ks = 0; ks < 2; ++ks) {
        s16x8 wh[4], wlv[4], ah[4], alv[4];
#pragma unroll
        for (int mi = 0; mi < 4; ++mi) {
          int row = wm * 64 + mi * 16 + rowA;
          int idx = row * 64 + (((ks * 4 + kg) ^ (row & 7)) << 3);
          wh[mi]  = *(const s16x8*)&WHs[idx];
          wlv[mi] = *(const s16x8*)&WLs[idx];
        }
#pragma unroll
        for (int ni = 0; ni < 4; ++ni) {
          int row = wn * 64 + ni * 16 + rowA;
          int idx = row * 64 + (((ks * 4 + kg) ^ (row & 7)) << 3);
          ah[ni]  = *(const s16x8*)&AHs[idx];
          alv[ni] = *(const s16x8*)&ALs[idx];
        }
#pragma unroll
        for (int mi = 0; mi < 4; ++mi)
#pragma unroll
          for (int ni = 0; ni < 4; ++ni) {
            acc[mi][ni] = __builtin_amdgcn_mfma_f32_16x16x32_bf16(wh[mi],  ah[ni],  acc[mi][ni], 0, 0, 0);
            acc[mi][ni] = __builtin_amdgcn_mfma_f32_16x16x32_bf16(wh[mi],  alv[ni], acc[mi][ni], 0, 0, 0);
            acc[mi][ni] = __builtin_amdgcn_mfma_f32_16x16x32_bf16(wlv[mi], ah[ni],  acc[mi][ni], 0, 0, 0);
          }
      }
      __syncthreads();
    }
    if (pass == 0 && isZ) {
#pragma unroll
      for (int mi = 0; mi < 4; ++mi)
#pragma unroll
        for (int ni = 0; ni < 4; ++ni)
#pragma unroll
          for (int r = 0; r < 4; ++r) acc[mi][ni][r] = fmaxf(acc[mi][ni][r], 0.f);
    }
  }
  const int orow = (lane >> 4) * 4, pcol = lane & 15;
#pragma unroll
  for (int mi = 0; mi < 4; ++mi)
#pragma unroll
    for (int ni = 0; ni < 4; ++ni)
#pragma unroll
      for (int r = 0; r < 4; ++r)
        out[(size_t)(ob + wm * 64 + mi * 16 + orow + r) * PIX +
            pb + wn * 64 + ni * 16 + pcol] = acc[mi][ni][r];
}

// ---------------- Chan-Vese (packed-fp32 v_pk_* math) ----------------
__device__ __forceinline__ float fast_atan(float x) {
  float a = __builtin_fabsf(x);
  float inv = __builtin_amdgcn_rcpf(a);
  bool big = a > 1.f;
  float tt = big ? inv : a;
  float t2 = tt * tt;
  float p = fmaf(t2, 0.0208351f, -0.0851330f);
  p = fmaf(t2, p, 0.1801410f);
  p = fmaf(t2, p, -0.3302995f);
  p = fmaf(t2, p, 0.9998660f);
  p = p * tt;
  float r = big ? (1.57079632679f - p) : p;
  return __builtin_copysignf(r, x);
}

// (256,4): VGPR cap 128 — (256,6) previously forced VGPR=40 and spilled
// everything to scratch (2.1 GB HBM). Occupancy comes from LDS: 29.7KB -> 5/CU.
__global__ __launch_bounds__(256, 4) void chanvese(
    const float* __restrict__ zb, float* __restrict__ ob,
    const float* __restrict__ dtp, const float* __restrict__ lamp)
{
  __shared__ float phi_l[64 * CV_PITCH];     // 20480 B
  __shared__ unsigned ny_l[64 * NY_PITCH];   // 9216 B (bf16x2)
  __shared__ float red[12];
  const int t = threadIdx.x;
  const int lane = t & 63, wv = t >> 6;
  const int row = t >> 2, s = t & 3;
  const size_t gbase = (size_t)blockIdx.x * PIX + row * 64 + s * 16;
  const float dtv = dtp[0], lam = lamp[0];
  const float INV_PI = 0.31830988618379067f;
  const float dtpi = dtv * INV_PI;
  const float fy = (row == 0 || row == 63) ? 1.f : 0.5f;
  const float exl = (s == 0) ? 2.f : 1.f;   // edge one-sided factor fix
  const float exr = (s == 3) ? 2.f : 1.f;
  const int my  = row * CV_PITCH + s * CV_SSTR;
  const int ub  = ((row == 0) ? 0 : row - 1) * CV_PITCH + s * CV_SSTR;
  const int db  = ((row == 63) ? 63 : row + 1) * CV_PITCH + s * CV_SSTR;
  const int myn = row * NY_PITCH + s * 8;
  const int ubn = ((row == 0) ? 0 : row - 1) * NY_PITCH + s * 8;
  const int dbn = ((row == 63) ? 63 : row + 1) * NY_PITCH + s * 8;
  const f32x2 eps2 = {1e-8f, 1e-8f};

  f32x2 I2[8], ph2[8], nx2[8];
#pragma unroll
  for (int q = 0; q < 4; ++q) {
    f32x4 iv = *(const f32x4*)(zb + gbase + q * 4);
    f32x4 pv = *(const f32x4*)(ob + gbase + q * 4);
    I2[2 * q]     = (f32x2){iv[0], iv[1]};
    I2[2 * q + 1] = (f32x2){iv[2], iv[3]};
    ph2[2 * q]     = (f32x2){pv[0], pv[1]};
    ph2[2 * q + 1] = (f32x2){pv[2], pv[3]};
    *(f32x4*)&phi_l[my + q * 4] = pv;
  }
  float sI = 0.f, s_at = 0.f, s_iat = 0.f;
#pragma unroll
  for (int p = 0; p < 8; ++p) {
    sI += I2[p].x + I2[p].y;
    float a0 = fast_atan(ph2[p].x), a1 = fast_atan(ph2[p].y);
    s_at += a0 + a1;
    s_iat = fmaf(I2[p].x, a0, fmaf(I2[p].y, a1, s_iat));
  }
#pragma unroll
  for (int off = 32; off; off >>= 1) {
    sI += __shfl_xor(sI, off);
    s_at += __shfl_xor(s_at, off);
    s_iat += __shfl_xor(s_iat, off);
  }
  if (lane == 0) { red[wv] = s_at; red[4 + wv] = s_iat; red[8 + wv] = sI; }
  __syncthreads();
  float S_at = red[0] + red[1] + red[2] + red[3];
  float S_iat = red[4] + red[5] + red[6] + red[7];
  const float sumI = red[8] + red[9] + red[10] + red[11];

  for (int it = 0; it < 10; ++it) {
    float a1 = fmaf(INV_PI, S_at, 2048.f);
    float sIH = fmaf(INV_PI, S_iat, 0.5f * sumI);
    float c1 = sIH * __builtin_amdgcn_rcpf(a1 + 1e-8f);
    float c2 = (sumI - sIH) * __builtin_amdgcn_rcpf(4096.f - a1 + 1e-8f);
    float lam12 = lam * (c1 - c2);
    float ms12 = -(c1 + c2);

    // ---- pass 1: normals (packed pairs); nx in regs, ny -> LDS bf16x2 ----
    float ls = __shfl(ph2[7].y, lane - 1);
    float rs = __shfl(ph2[0].x, lane + 1);
    float lb = (s == 0) ? ph2[0].x : ls;
    float rb = (s == 3) ? ph2[7].y : rs;
    unsigned nyp[8];
#pragma unroll
    for (int q = 0; q < 4; ++q) {
      f32x4 uv = *(const f32x4*)&phi_l[ub + q * 4];
      f32x4 dv = *(const f32x4*)&phi_l[db + q * 4];
#pragma unroll
      for (int e = 0; e < 2; ++e) {
        const int p = 2 * q + e;
        f32x2 u2 = (f32x2){uv[2 * e], uv[2 * e + 1]};
        f32x2 d2 = (f32x2){dv[2 * e], dv[2 * e + 1]};
        f32x2 py = (d2 - u2) * fy;
        f32x2 L = {(p == 0) ? lb : ph2[p - 1].y, ph2[p].x};
        f32x2 R = {ph2[p].y, (p == 7) ? rb : ph2[p + 1].x};
        f32x2 px = (R - L) * 0.5f;
        if (p == 0) px.x *= exl;
        if (p == 7) px.y *= exr;
        f32x2 qq = px * px + (py * py + eps2);
        f32x2 rn = {__builtin_amdgcn_rsqf(qq.x), __builtin_amdgcn_rsqf(qq.y)};
        nx2[p] = px * rn;
        f32x2 nyv = py * rn;
        float nlo = nyv.x, nhi = nyv.y;
        unsigned pk;
        asm("v_cvt_pk_bf16_f32 %0, %1, %2" : "=v"(pk) : "v"(nlo), "v"(nhi));
        nyp[p] = pk;
      }
    }
    *(uint4*)&ny_l[myn]     = make_uint4(nyp[0], nyp[1], nyp[2], nyp[3]);
    *(uint4*)&ny_l[myn + 4] = make_uint4(nyp[4], nyp[5], nyp[6], nyp[7]);
    __syncthreads();

    // ---- pass 2: curvature + update + incremental sums (packed) ----
    float nls = __shfl(nx2[7].y, lane - 1);
    float nrs = __shfl(nx2[0].x, lane + 1);
    float nlb = (s == 0) ? nx2[0].x : nls;
    float nrb = (s == 3) ? nx2[7].y : nrs;
    f32x2 inc_at2 = {0.f, 0.f}, inc_iat2 = {0.f, 0.f};
#pragma unroll
    for (int h = 0; h < 2; ++h) {
      uint4 au = *(const uint4*)&ny_l[ubn + 4 * h];
      uint4 ad = *(const uint4*)&ny_l[dbn + 4 * h];
      unsigned ua[4] = {au.x, au.y, au.z, au.w};
      unsigned ud[4] = {ad.x, ad.y, ad.z, ad.w};
      f32x2 phs[4];
#pragma unroll
      for (int e = 0; e < 4; ++e) {
        const int p = 4 * h + e;
        f32x2 nyu = {__uint_as_float(ua[e] << 16), __uint_as_float(ua[e] & 0xffff0000u)};
        f32x2 nyd = {__uint_as_float(ud[e] << 16), __uint_as_float(ud[e] & 0xffff0000u)};
        f32x2 dny = (nyd - nyu) * fy;
        f32x2 L = {(p == 0) ? nlb : nx2[p - 1].y, nx2[p].x};
        f32x2 R = {nx2[p].y, (p == 7) ? nrb : nx2[p + 1].x};
        f32x2 dnx = (R - L) * 0.5f;
        if (p == 0) dnx.x *= exl;
        if (p == 7) dnx.y *= exr;
        f32x2 curv = dnx + dny;
        f32x2 c = ph2[p];
        f32x2 den = c * c + (f32x2){1.f, 1.f};
        f32x2 rcd = {__builtin_amdgcn_rcpf(den.x), __builtin_amdgcn_rcpf(den.y)};
        f32x2 tI = I2[p] * 2.f + ms12;
        f32x2 force = tI * lam12 + curv;
        f32x2 dphi = (rcd * dtpi) * force;
        f32x2 pn = c + dphi;
        ph2[p] = pn;
        phs[e] = pn;
        f32x2 da = dphi * rcd;
        inc_at2 += da;
        inc_iat2 = I2[p] * da + inc_iat2;
      }
      if (it < 9) {
        *(f32x4*)&phi_l[my + 8 * h] =
            (f32x4){phs[0].x, phs[0].y, phs[1].x, phs[1].y};
        *(f32x4*)&phi_l[my + 8 * h + 4] =
            (f32x4){phs[2].x, phs[2].y, phs[3].x, phs[3].y};
      }
    }
    if (it < 9) {
      float inc_at = inc_at2.x + inc_at2.y;
      float inc_iat = inc_iat2.x + inc_iat2.y;
#pragma unroll
      for (int off = 32; off; off >>= 1) {
        inc_at += __shfl_xor(inc_at, off);
        inc_iat += __shfl_xor(inc_iat, off);
      }
      if (lane == 0) { red[2 * wv] = inc_at; red[2 * wv + 1] = inc_iat; }
      __syncthreads();
      S_at += red[0] + red[2] + red[4] + red[6];
      S_iat += red[1] + red[3] + red[5] + red[7];
    }
  }

#pragma unroll
  for (int q = 0; q < 4; ++q) {
    f32x2 pa = ph2[2 * q], pb2 = ph2[2 * q + 1];
    float o0 = 1.f / (1.f + exp2f(pa.x * -1.44269504089f));
    float o1 = 1.f / (1.f + exp2f(pa.y * -1.44269504089f));
    float o2 = 1.f / (1.f + exp2f(pb2.x * -1.44269504089f));
    float o3 = 1.f / (1.f + exp2f(pb2.y * -1.44269504089f));
    *(float4*)(ob + gbase + q * 4) = make_float4(o0, o1, o2, o3);
  }
}

extern "C" void kernel_launch(void* const* d_in, const int* in_sizes, int n_in,
                              void* d_out, int out_size, void* d_ws, size_t ws_size,
                              hipStream_t stream)
{
  const float* contour = (const float*)d_in[0];
  const float* g       = (const float*)d_in[1];
  const float* x       = (const float*)d_in[2];
  const float* dt      = (const float*)d_in[3];
  const float* lam     = (const float*)d_in[4];
  const float* g_w     = (const float*)d_in[5];
  const float* x_w     = (const float*)d_in[6];
  const float* c_w     = (const float*)d_in[7];
  float* out = (float*)d_out;
  float* z   = (float*)d_ws;  // [8,512,64,64] f32 = 67 MB

  mfma_gemm_all<<<dim3(32, 4, 16), dim3(256), 0, stream>>>(
      g, x, contour, g_w, x_w, c_w, z, out);
  chanvese<<<dim3(4096), dim3(256), 0, stream>>>(z, out, dt, lam);
}

// Round 8
// 246.046 us; speedup vs baseline: 2.6676x; 1.1541x over previous
//
#include <hip/hip_runtime.h>
#include <math.h>

#define PIX 4096
#define O_CH 512
#define CV_PITCH 80   // f32 words per phi row in LDS (s-stride 20 -> conflict-free)
#define CV_SSTR 20
#define NY_PITCH 36   // u32 per ny row (s-stride 8 -> conflict-free)

// bf16 weight-plane offsets (ushorts): g[512x256], x[512x512], c[512x256]
#define WOFF_G 0
#define WOFF_X 131072
#define WOFF_C 393216
#define W_ELEMS 524288

typedef __attribute__((ext_vector_type(8))) short s16x8;
typedef __attribute__((ext_vector_type(4))) float f32x4;
typedef __attribute__((ext_vector_type(2))) float f32x2;

__device__ __forceinline__ unsigned cvt_pk_bf16(float a, float b) {
  unsigned r;
  asm("v_cvt_pk_bf16_f32 %0, %1, %2" : "=v"(r) : "v"(a), "v"(b));
  return r;
}

// ---------------- weight pre-conversion: f32 -> bf16 hi/lo planes ----------------
__global__ __launch_bounds__(256) void conv_w(
    const float* __restrict__ gw, const float* __restrict__ xw,
    const float* __restrict__ cw,
    ushort* __restrict__ WH, ushort* __restrict__ WL)
{
  const int r = blockIdx.y;
  const float* src = (r == 0) ? gw : ((r == 1) ? xw : cw);
  const int n4 = (r == 1) ? 65536 : 32768;   // float4 count
  const int doff = (r == 0) ? WOFF_G : ((r == 1) ? WOFF_X : WOFF_C);
  const int i = blockIdx.x * 256 + threadIdx.x;
  if (i >= n4) return;
  float4 v = ((const float4*)src)[i];
  unsigned h01 = cvt_pk_bf16(v.x, v.y);
  unsigned h23 = cvt_pk_bf16(v.z, v.w);
  float l0 = v.x - __uint_as_float(h01 << 16);
  float l1 = v.y - __uint_as_float(h01 & 0xffff0000u);
  float l2 = v.z - __uint_as_float(h23 << 16);
  float l3 = v.w - __uint_as_float(h23 & 0xffff0000u);
  unsigned lo01 = cvt_pk_bf16(l0, l1);
  unsigned lo23 = cvt_pk_bf16(l2, l3);
  ((uint2*)(WH + doff))[i] = make_uint2(h01, h23);
  ((uint2*)(WL + doff))[i] = make_uint2(lo01, lo23);
}

// ---------------- merged MFMA GEMM (split-bf16, ~fp32 accurate) ----------------
// bz<8: z[b] = relu(g_w*g[b]) + x_w*x[b];  bz>=8: phi0[b] = c_w*contour[b]
__global__ __launch_bounds__(256, 2) void mfma_gemm_all(
    const float* __restrict__ g, const float* __restrict__ x,
    const float* __restrict__ contour,
    const ushort* __restrict__ WHg, const ushort* __restrict__ WLg,
    float* __restrict__ z, float* __restrict__ phi0)
{
  __shared__ ushort WHs[8192], WLs[8192], AHs[8192], ALs[8192];  // 64 KB
  const int t = threadIdx.x;
  const int lane = t & 63, wave = t >> 6;
  const int wm = wave >> 1, wn = wave & 1;
  const int rowA = lane & 15, kg = lane >> 4;
  const int pb = blockIdx.x * 128, ob = blockIdx.y * 128;
  const int bz = blockIdx.z;
  const bool isZ = bz < 8;
  const int b = isZ ? bz : bz - 8;

  const int woff1 = isZ ? WOFF_G : WOFF_C;
  const int K1 = 256;
  const float* A1 = (isZ ? g : contour) + (size_t)b * K1 * PIX;
  const int K2 = 512;
  const float* A2 = isZ ? x + (size_t)b * K2 * PIX : nullptr;
  float* out = (isZ ? z : phi0) + (size_t)b * O_CH * PIX;

  f32x4 acc[4][4];
#pragma unroll
  for (int mi = 0; mi < 4; ++mi)
#pragma unroll
    for (int ni = 0; ni < 4; ++ni) acc[mi][ni] = (f32x4){0.f, 0.f, 0.f, 0.f};

  for (int pass = 0; pass < 2; ++pass) {
    if (pass == 1 && A2 == nullptr) break;
    const int K = pass ? K2 : K1;
    const int woff = pass ? WOFF_X : woff1;
    const float* A = pass ? A2 : A1;

    for (int kb = 0; kb < K; kb += 64) {
      // ---- stage W tile [128 o][64 k] from pre-converted bf16 planes ----
      {
        const int o_r = t >> 1, hf = t & 1;
        const size_t wbase = (size_t)woff + (size_t)(ob + o_r) * K + kb + hf * 32;
        const ushort* whrow = WHg + wbase;
        const ushort* wlrow = WLg + wbase;
#pragma unroll
        for (int i = 0; i < 4; ++i) {
          int idx = o_r * 64 + (((hf * 4 + i) ^ (o_r & 7)) << 3);
          *(s16x8*)&WHs[idx] = *(const s16x8*)(whrow + i * 8);
          *(s16x8*)&WLs[idx] = *(const s16x8*)(wlrow + i * 8);
        }
      }
      // ---- stage A tile transposed to [128 p][64 k], cvt_pk hi/lo ----
#pragma unroll
      for (int ph = 0; ph < 2; ++ph) {
        const int rp = ph * 64 + lane;
        const float* ac = A + (size_t)kb * PIX + pb + rp;
#pragma unroll
        for (int ch = 0; ch < 2; ++ch) {
          const int kloc0 = ch * 32 + wave * 8;
          float v[8];
#pragma unroll
          for (int j = 0; j < 8; ++j) v[j] = ac[(size_t)(kloc0 + j) * PIX];
          unsigned h[4], l[4];
#pragma unroll
          for (int j2 = 0; j2 < 4; ++j2) {
            h[j2] = cvt_pk_bf16(v[2 * j2], v[2 * j2 + 1]);
            float lo0 = v[2 * j2] - __uint_as_float(h[j2] << 16);
            float lo1 = v[2 * j2 + 1] - __uint_as_float(h[j2] & 0xffff0000u);
            l[j2] = cvt_pk_bf16(lo0, lo1);
          }
          int grp = ch * 4 + wave;
          int idx = rp * 64 + ((grp ^ (rp & 7)) << 3);
          *(uint4*)&AHs[idx] = make_uint4(h[0], h[1], h[2], h[3]);
          *(uint4*)&ALs[idx] = make_uint4(l[0], l[1], l[2], l[3]);
        }
      }
      __syncthreads();
      // ---- compute: 3 split-passes, 96 MFMA per wave per K-step ----
#pragma unroll
      for (int ks = 0; ks < 2; ++ks) {
        s16x8 wh[4], wlv[4], ah[4], alv[4];
#pragma unroll
        for (int mi = 0; mi < 4; ++mi) {
          int row = wm * 64 + mi * 16 + rowA;
          int idx = row * 64 + (((ks * 4 + kg) ^ (row & 7)) << 3);
          wh[mi]  = *(const s16x8*)&WHs[idx];
          wlv[mi] = *(const s16x8*)&WLs[idx];
        }
#pragma unroll
        for (int ni = 0; ni < 4; ++ni) {
          int row = wn * 64 + ni * 16 + rowA;
          int idx = row * 64 + (((ks * 4 + kg) ^ (row & 7)) << 3);
          ah[ni]  = *(const s16x8*)&AHs[idx];
          alv[ni] = *(const s16x8*)&ALs[idx];
        }
#pragma unroll
        for (int mi = 0; mi < 4; ++mi)
#pragma unroll
          for (int ni = 0; ni < 4; ++ni) {
            acc[mi][ni] = __builtin_amdgcn_mfma_f32_16x16x32_bf16(wh[mi],  ah[ni],  acc[mi][ni], 0, 0, 0);
            acc[mi][ni] = __builtin_amdgcn_mfma_f32_16x16x32_bf16(wh[mi],  alv[ni], acc[mi][ni], 0, 0, 0);
            acc[mi][ni] = __builtin_amdgcn_mfma_f32_16x16x32_bf16(wlv[mi], ah[ni],  acc[mi][ni], 0, 0, 0);
          }
      }
      __syncthreads();
    }
    if (pass == 0 && isZ) {
#pragma unroll
      for (int mi = 0; mi < 4; ++mi)
#pragma unroll
        for (int ni = 0; ni < 4; ++ni)
#pragma unroll
          for (int r = 0; r < 4; ++r) acc[mi][ni][r] = fmaxf(acc[mi][ni][r], 0.f);
    }
  }
  const int orow = (lane >> 4) * 4, pcol = lane & 15;
#pragma unroll
  for (int mi = 0; mi < 4; ++mi)
#pragma unroll
    for (int ni = 0; ni < 4; ++ni)
#pragma unroll
      for (int r = 0; r < 4; ++r)
        out[(size_t)(ob + wm * 64 + mi * 16 + orow + r) * PIX +
            pb + wn * 64 + ni * 16 + pcol] = acc[mi][ni][r];
}

// ---------------- Chan-Vese (packed-fp32 math) ----------------
__device__ __forceinline__ float fast_atan(float x) {
  float a = __builtin_fabsf(x);
  float inv = __builtin_amdgcn_rcpf(a);
  bool big = a > 1.f;
  float tt = big ? inv : a;
  float t2 = tt * tt;
  float p = fmaf(t2, 0.0208351f, -0.0851330f);
  p = fmaf(t2, p, 0.1801410f);
  p = fmaf(t2, p, -0.3302995f);
  p = fmaf(t2, p, 0.9998660f);
  p = p * tt;
  float r = big ? (1.57079632679f - p) : p;
  return __builtin_copysignf(r, x);
}

// (256,4): VGPR cap 128 — (256,6) forced VGPR=40 and spilled to scratch.
__global__ __launch_bounds__(256, 4) void chanvese(
    const float* __restrict__ zb, float* __restrict__ ob,
    const float* __restrict__ dtp, const float* __restrict__ lamp)
{
  __shared__ float phi_l[64 * CV_PITCH];     // 20480 B
  __shared__ unsigned ny_l[64 * NY_PITCH];   // 9216 B (bf16x2)
  __shared__ float red[12];
  const int t = threadIdx.x;
  const int lane = t & 63, wv = t >> 6;
  const int row = t >> 2, s = t & 3;
  const size_t gbase = (size_t)blockIdx.x * PIX + row * 64 + s * 16;
  const float dtv = dtp[0], lam = lamp[0];
  const float INV_PI = 0.31830988618379067f;
  const float dtpi = dtv * INV_PI;
  const float fy = (row == 0 || row == 63) ? 1.f : 0.5f;
  const float exl = (s == 0) ? 2.f : 1.f;
  const float exr = (s == 3) ? 2.f : 1.f;
  const int my  = row * CV_PITCH + s * CV_SSTR;
  const int ub  = ((row == 0) ? 0 : row - 1) * CV_PITCH + s * CV_SSTR;
  const int db  = ((row == 63) ? 63 : row + 1) * CV_PITCH + s * CV_SSTR;
  const int myn = row * NY_PITCH + s * 8;
  const int ubn = ((row == 0) ? 0 : row - 1) * NY_PITCH + s * 8;
  const int dbn = ((row == 63) ? 63 : row + 1) * NY_PITCH + s * 8;
  const f32x2 eps2 = {1e-8f, 1e-8f};

  f32x2 I2[8], ph2[8], nx2[8];
#pragma unroll
  for (int q = 0; q < 4; ++q) {
    f32x4 iv = *(const f32x4*)(zb + gbase + q * 4);
    f32x4 pv = *(const f32x4*)(ob + gbase + q * 4);
    I2[2 * q]     = (f32x2){iv[0], iv[1]};
    I2[2 * q + 1] = (f32x2){iv[2], iv[3]};
    ph2[2 * q]     = (f32x2){pv[0], pv[1]};
    ph2[2 * q + 1] = (f32x2){pv[2], pv[3]};
    *(f32x4*)&phi_l[my + q * 4] = pv;
  }
  float sI = 0.f, s_at = 0.f, s_iat = 0.f;
#pragma unroll
  for (int p = 0; p < 8; ++p) {
    sI += I2[p].x + I2[p].y;
    float a0 = fast_atan(ph2[p].x), a1 = fast_atan(ph2[p].y);
    s_at += a0 + a1;
    s_iat = fmaf(I2[p].x, a0, fmaf(I2[p].y, a1, s_iat));
  }
#pragma unroll
  for (int off = 32; off; off >>= 1) {
    sI += __shfl_xor(sI, off);
    s_at += __shfl_xor(s_at, off);
    s_iat += __shfl_xor(s_iat, off);
  }
  if (lane == 0) { red[wv] = s_at; red[4 + wv] = s_iat; red[8 + wv] = sI; }
  __syncthreads();
  float S_at = red[0] + red[1] + red[2] + red[3];
  float S_iat = red[4] + red[5] + red[6] + red[7];
  const float sumI = red[8] + red[9] + red[10] + red[11];

  for (int it = 0; it < 10; ++it) {
    float a1 = fmaf(INV_PI, S_at, 2048.f);
    float sIH = fmaf(INV_PI, S_iat, 0.5f * sumI);
    float c1 = sIH * __builtin_amdgcn_rcpf(a1 + 1e-8f);
    float c2 = (sumI - sIH) * __builtin_amdgcn_rcpf(4096.f - a1 + 1e-8f);
    float lam12 = lam * (c1 - c2);
    float ms12 = -(c1 + c2);

    // ---- pass 1: normals (packed pairs); nx in regs, ny -> LDS bf16x2 ----
    float ls = __shfl(ph2[7].y, lane - 1);
    float rs = __shfl(ph2[0].x, lane + 1);
    float lb = (s == 0) ? ph2[0].x : ls;
    float rb = (s == 3) ? ph2[7].y : rs;
    unsigned nyp[8];
#pragma unroll
    for (int q = 0; q < 4; ++q) {
      f32x4 uv = *(const f32x4*)&phi_l[ub + q * 4];
      f32x4 dv = *(const f32x4*)&phi_l[db + q * 4];
#pragma unroll
      for (int e = 0; e < 2; ++e) {
        const int p = 2 * q + e;
        f32x2 u2 = (f32x2){uv[2 * e], uv[2 * e + 1]};
        f32x2 d2 = (f32x2){dv[2 * e], dv[2 * e + 1]};
        f32x2 py = (d2 - u2) * fy;
        f32x2 L = {(p == 0) ? lb : ph2[p - 1].y, ph2[p].x};
        f32x2 R = {ph2[p].y, (p == 7) ? rb : ph2[p + 1].x};
        f32x2 px = (R - L) * 0.5f;
        if (p == 0) px.x *= exl;
        if (p == 7) px.y *= exr;
        f32x2 qq = px * px + (py * py + eps2);
        f32x2 rn = {__builtin_amdgcn_rsqf(qq.x), __builtin_amdgcn_rsqf(qq.y)};
        nx2[p] = px * rn;
        f32x2 nyv = py * rn;
        nyp[p] = cvt_pk_bf16(nyv.x, nyv.y);
      }
    }
    *(uint4*)&ny_l[myn]     = make_uint4(nyp[0], nyp[1], nyp[2], nyp[3]);
    *(uint4*)&ny_l[myn + 4] = make_uint4(nyp[4], nyp[5], nyp[6], nyp[7]);
    __syncthreads();

    // ---- pass 2: curvature + update + incremental sums (packed) ----
    float nls = __shfl(nx2[7].y, lane - 1);
    float nrs = __shfl(nx2[0].x, lane + 1);
    float nlb = (s == 0) ? nx2[0].x : nls;
    float nrb = (s == 3) ? nx2[7].y : nrs;
    f32x2 inc_at2 = {0.f, 0.f}, inc_iat2 = {0.f, 0.f};
#pragma unroll
    for (int h = 0; h < 2; ++h) {
      uint4 au = *(const uint4*)&ny_l[ubn + 4 * h];
      uint4 ad = *(const uint4*)&ny_l[dbn + 4 * h];
      unsigned ua[4] = {au.x, au.y, au.z, au.w};
      unsigned ud[4] = {ad.x, ad.y, ad.z, ad.w};
      f32x2 phs[4];
#pragma unroll
      for (int e = 0; e < 4; ++e) {
        const int p = 4 * h + e;
        f32x2 nyu = {__uint_as_float(ua[e] << 16), __uint_as_float(ua[e] & 0xffff0000u)};
        f32x2 nyd = {__uint_as_float(ud[e] << 16), __uint_as_float(ud[e] & 0xffff0000u)};
        f32x2 dny = (nyd - nyu) * fy;
        f32x2 L = {(p == 0) ? nlb : nx2[p - 1].y, nx2[p].x};
        f32x2 R = {nx2[p].y, (p == 7) ? nrb : nx2[p + 1].x};
        f32x2 dnx = (R - L) * 0.5f;
        if (p == 0) dnx.x *= exl;
        if (p == 7) dnx.y *= exr;
        f32x2 curv = dnx + dny;
        f32x2 c = ph2[p];
        f32x2 den = c * c + (f32x2){1.f, 1.f};
        f32x2 rcd = {__builtin_amdgcn_rcpf(den.x), __builtin_amdgcn_rcpf(den.y)};
        f32x2 tI = I2[p] * 2.f + ms12;
        f32x2 force = tI * lam12 + curv;
        f32x2 dphi = (rcd * dtpi) * force;
        f32x2 pn = c + dphi;
        ph2[p] = pn;
        phs[e] = pn;
        f32x2 da = dphi * rcd;
        inc_at2 += da;
        inc_iat2 = I2[p] * da + inc_iat2;
      }
      if (it < 9) {
        *(f32x4*)&phi_l[my + 8 * h] =
            (f32x4){phs[0].x, phs[0].y, phs[1].x, phs[1].y};
        *(f32x4*)&phi_l[my + 8 * h + 4] =
            (f32x4){phs[2].x, phs[2].y, phs[3].x, phs[3].y};
      }
    }
    if (it < 9) {
      float inc_at = inc_at2.x + inc_at2.y;
      float inc_iat = inc_iat2.x + inc_iat2.y;
#pragma unroll
      for (int off = 32; off; off >>= 1) {
        inc_at += __shfl_xor(inc_at, off);
        inc_iat += __shfl_xor(inc_iat, off);
      }
      if (lane == 0) { red[2 * wv] = inc_at; red[2 * wv + 1] = inc_iat; }
      __syncthreads();
      S_at += red[0] + red[2] + red[4] + red[6];
      S_iat += red[1] + red[3] + red[5] + red[7];
    }
  }

#pragma unroll
  for (int q = 0; q < 4; ++q) {
    f32x2 pa = ph2[2 * q], pb2 = ph2[2 * q + 1];
    float o0 = 1.f / (1.f + exp2f(pa.x * -1.44269504089f));
    float o1 = 1.f / (1.f + exp2f(pa.y * -1.44269504089f));
    float o2 = 1.f / (1.f + exp2f(pb2.x * -1.44269504089f));
    float o3 = 1.f / (1.f + exp2f(pb2.y * -1.44269504089f));
    *(float4*)(ob + gbase + q * 4) = make_float4(o0, o1, o2, o3);
  }
}

extern "C" void kernel_launch(void* const* d_in, const int* in_sizes, int n_in,
                              void* d_out, int out_size, void* d_ws, size_t ws_size,
                              hipStream_t stream)
{
  const float* contour = (const float*)d_in[0];
  const float* g       = (const float*)d_in[1];
  const float* x       = (const float*)d_in[2];
  const float* dt      = (const float*)d_in[3];
  const float* lam     = (const float*)d_in[4];
  const float* g_w     = (const float*)d_in[5];
  const float* x_w     = (const float*)d_in[6];
  const float* c_w     = (const float*)d_in[7];
  float* out = (float*)d_out;
  float* z   = (float*)d_ws;                       // [8,512,64,64] f32 = 64 MiB
  ushort* WH = (ushort*)(z + (size_t)8 * O_CH * PIX);  // +64 MiB
  ushort* WL = WH + W_ELEMS;                       // +1.25 MiB

  conv_w<<<dim3(256, 3), dim3(256), 0, stream>>>(g_w, x_w, c_w, WH, WL);
  mfma_gemm_all<<<dim3(32, 4, 16), dim3(256), 0, stream>>>(
      g, x, contour, WH, WL, z, out);
  chanvese<<<dim3(4096), dim3(256), 0, stream>>>(z, out, dt, lam);
}